// Round 1
// baseline (91.114 us; speedup 1.0000x reference)
//
#include <hip/hip_runtime.h>

// Patch gather: out[n, r, c] = images[(p0[n] + r) * W + p1[n] + c]
// Fixed problem geometry (from setup_inputs): H = W = 4096, width = 128, N = 4096.
//
// One block per patch. 256 threads; each thread handles 16 float4-sized
// output chunks (4096 float4 per patch / 256 threads). Output stores are
// 16B-aligned float4; input loads are 4 scalar floats (p1 has random
// alignment so float4 input loads would be UB / misaligned).

#define IMG_W   4096
#define PATCH_W 128
#define F4_PER_PATCH (PATCH_W * PATCH_W / 4)   // 4096
#define BLOCK   256

__global__ __launch_bounds__(BLOCK) void patch_gather_kernel(
    const float* __restrict__ images,
    const int*   __restrict__ positions,
    float*       __restrict__ out)
{
    const int n  = blockIdx.x;
    const int p0 = positions[2 * n];       // row of patch min-corner
    const int p1 = positions[2 * n + 1];   // col of patch min-corner

    const float* src = images + (size_t)p0 * IMG_W + p1;
    float*       dst = out + (size_t)n * (PATCH_W * PATCH_W);

    #pragma unroll
    for (int it = 0; it < F4_PER_PATCH / BLOCK; ++it) {
        const int i  = it * BLOCK + threadIdx.x;   // float4 index within patch
        const int r  = i >> 5;                     // i / 32 (32 float4 per row)
        const int c  = (i & 31) << 2;              // (i % 32) * 4

        const float* s = src + (size_t)r * IMG_W + c;
        float4 v;
        v.x = s[0];
        v.y = s[1];
        v.z = s[2];
        v.w = s[3];
        *reinterpret_cast<float4*>(dst + (size_t)r * PATCH_W + c) = v;
    }
}

extern "C" void kernel_launch(void* const* d_in, const int* in_sizes, int n_in,
                              void* d_out, int out_size, void* d_ws, size_t ws_size,
                              hipStream_t stream) {
    const float* images    = (const float*)d_in[0];
    const int*   positions = (const int*)d_in[1];
    // d_in[2] = width scalar (=128), fixed at compile time.
    float* out = (float*)d_out;

    const int N = in_sizes[1] / 2;   // 4096 patches

    patch_gather_kernel<<<N, BLOCK, 0, stream>>>(images, positions, out);
}

// Round 3
// 89.340 us; speedup vs baseline: 1.0199x; 1.0199x over previous
//
#include <hip/hip_runtime.h>

// Patch gather: out[n, r, c] = images[(p0[n] + r) * W + p1[n] + c]
// Fixed geometry: H = W = 4096, width = 128, N = 4096.
//
// One block per patch, 256 threads, 16 float4 chunks per thread.
// Stores are NON-TEMPORAL: the 268 MB output stream would otherwise thrash
// the 256 MiB Infinity Cache and evict the 64 MiB image (which has 4x read
// reuse). nt stores keep the image L3-resident so reads don't hit HBM.
// __builtin_nontemporal_store needs a NATIVE clang vector type, not
// HIP_vector_type (float4) -> use ext_vector_type(4).

#define IMG_W   4096
#define PATCH_W 128
#define F4_PER_PATCH (PATCH_W * PATCH_W / 4)   // 4096
#define BLOCK   256

typedef float f32x4 __attribute__((ext_vector_type(4)));

__global__ __launch_bounds__(BLOCK) void patch_gather_kernel(
    const float* __restrict__ images,
    const int*   __restrict__ positions,
    float*       __restrict__ out)
{
    const int n  = blockIdx.x;
    const int p0 = positions[2 * n];       // row of patch min-corner
    const int p1 = positions[2 * n + 1];   // col of patch min-corner

    const float* src = images + (size_t)p0 * IMG_W + p1;
    float*       dst = out + (size_t)n * (PATCH_W * PATCH_W);

    #pragma unroll
    for (int it = 0; it < F4_PER_PATCH / BLOCK; ++it) {
        const int i  = it * BLOCK + threadIdx.x;   // float4 index within patch
        const int r  = i >> 5;                     // i / 32 (32 float4 per row)
        const int c  = (i & 31) << 2;              // (i % 32) * 4

        const float* s = src + (size_t)r * IMG_W + c;
        f32x4 v;
        v.x = s[0];
        v.y = s[1];
        v.z = s[2];
        v.w = s[3];
        __builtin_nontemporal_store(v, reinterpret_cast<f32x4*>(dst + (size_t)r * PATCH_W + c));
    }
}

extern "C" void kernel_launch(void* const* d_in, const int* in_sizes, int n_in,
                              void* d_out, int out_size, void* d_ws, size_t ws_size,
                              hipStream_t stream) {
    const float* images    = (const float*)d_in[0];
    const int*   positions = (const int*)d_in[1];
    // d_in[2] = width scalar (=128), fixed at compile time.
    float* out = (float*)d_out;

    const int N = in_sizes[1] / 2;   // 4096 patches

    patch_gather_kernel<<<N, BLOCK, 0, stream>>>(images, positions, out);
}

// Round 4
// 66.136 us; speedup vs baseline: 1.3777x; 1.3509x over previous
//
#include <hip/hip_runtime.h>

// Patch gather: out[n, r, c] = images[(p0[n] + r) * W + p1[n] + c]
// Fixed geometry: H = W = 4096, width = 128, N = 4096.
//
// Two-kernel schedule:
//  1) order_kernel: single-block counting sort of patch indices by row band
//     (p0 >> 5, 128 buckets) into d_ws. ~4096 elements, a few us.
//  2) patch_gather_kernel: one block per patch, processed in band-sorted
//     order with a chunked XCD swizzle. All patches touching a given image
//     line now run within a ~11 MB traffic window, so the line stays in the
//     256 MiB Infinity Cache and is fetched from HBM once (~67 MB reads
//     instead of ~310 MB).
// Intra-bucket order from atomics is nondeterministic, but each patch writes
// only its own output slice -> output is deterministic.

#define IMG_W   4096
#define PATCH_W 128
#define F4_PER_PATCH (PATCH_W * PATCH_W / 4)   // 4096
#define BLOCK   256
#define NB      128   // row-band buckets (p0 >> 5, p0 < 4096)

typedef float f32x4 __attribute__((ext_vector_type(4)));

__global__ __launch_bounds__(1024) void order_kernel(
    const int* __restrict__ positions, int* __restrict__ order, int N)
{
    __shared__ int hist[NB];
    __shared__ int base[NB];
    const int tid = threadIdx.x;

    for (int b = tid; b < NB; b += blockDim.x) hist[b] = 0;
    __syncthreads();

    for (int i = tid; i < N; i += blockDim.x)
        atomicAdd(&hist[positions[2 * i] >> 5], 1);
    __syncthreads();

    if (tid == 0) {
        int s = 0;
        for (int b = 0; b < NB; ++b) { base[b] = s; s += hist[b]; }
    }
    __syncthreads();

    for (int b = tid; b < NB; b += blockDim.x) hist[b] = base[b];
    __syncthreads();

    for (int i = tid; i < N; i += blockDim.x) {
        const int slot = atomicAdd(&hist[positions[2 * i] >> 5], 1);
        order[slot] = i;
    }
}

__global__ __launch_bounds__(BLOCK) void patch_gather_kernel(
    const float* __restrict__ images,
    const int*   __restrict__ positions,
    const int*   __restrict__ order,     // may be null -> identity order
    float*       __restrict__ out,
    int N)
{
    int slot = blockIdx.x;
    if ((N & 7) == 0) {
        // chunked XCD swizzle: consecutive blocks round-robin across 8 XCDs;
        // give each XCD a contiguous chunk of the band-sorted patch list.
        const int nper = N >> 3;
        slot = (blockIdx.x & 7) * nper + (blockIdx.x >> 3);
    }
    const int n  = order ? order[slot] : slot;
    const int p0 = positions[2 * n];
    const int p1 = positions[2 * n + 1];

    const float* src = images + (size_t)p0 * IMG_W + p1;
    float*       dst = out + (size_t)n * (PATCH_W * PATCH_W);

    #pragma unroll
    for (int it = 0; it < F4_PER_PATCH / BLOCK; ++it) {
        const int i  = it * BLOCK + threadIdx.x;   // float4 index within patch
        const int r  = i >> 5;                     // i / 32 (32 float4 per row)
        const int c  = (i & 31) << 2;              // (i % 32) * 4

        const float* s = src + (size_t)r * IMG_W + c;
        f32x4 v;
        v.x = s[0];
        v.y = s[1];
        v.z = s[2];
        v.w = s[3];
        __builtin_nontemporal_store(v, reinterpret_cast<f32x4*>(dst + (size_t)r * PATCH_W + c));
    }
}

extern "C" void kernel_launch(void* const* d_in, const int* in_sizes, int n_in,
                              void* d_out, int out_size, void* d_ws, size_t ws_size,
                              hipStream_t stream) {
    const float* images    = (const float*)d_in[0];
    const int*   positions = (const int*)d_in[1];
    float* out = (float*)d_out;

    const int N = in_sizes[1] / 2;   // 4096 patches

    int* order = nullptr;
    if (ws_size >= (size_t)N * sizeof(int)) {
        order = (int*)d_ws;
        order_kernel<<<1, 1024, 0, stream>>>(positions, order, N);
    }
    patch_gather_kernel<<<N, BLOCK, 0, stream>>>(images, positions, order, out, N);
}